// Round 9
// baseline (275.444 us; speedup 1.0000x reference)
//
#include <hip/hip_runtime.h>
#include <hip/hip_bf16.h>
#include <math.h>

#define N_NODES 4096
#define NFEAT   1024
#define NHEADS  8
#define ALPHA   0.1f
#define MAXDEG  256

typedef short short8 __attribute__((ext_vector_type(8)));
typedef float f32x4  __attribute__((ext_vector_type(4)));

__device__ __forceinline__ ushort f2bf(float f) {
    uint b = __float_as_uint(f);
    b += 0x7FFFu + ((b >> 16) & 1u);            // RNE
    return (ushort)(b >> 16);
}
__device__ __forceinline__ float bf2f(ushort u) {
    return __uint_as_float(((uint)u) << 16);
}

// ---------------------------------------------------------------------------
// K1: merged prep. Blocks [0,4096): x -> x3 bf16 [hi|lo|hi].
// [4096,4224): W_heads transpose/split. [4224,4232): W_out.
// [4232,5256): build CSR (ushort) + dinv, 4 rows/block (one per wave).
// ---------------------------------------------------------------------------
__global__ __launch_bounds__(256) void prep_all(const float* __restrict__ x,
                                                const int* __restrict__ adj,
                                                const float* __restrict__ Whd,
                                                const float* __restrict__ Wo,
                                                short* __restrict__ x3,
                                                short* __restrict__ W3,
                                                short* __restrict__ W23,
                                                ushort* __restrict__ csr,
                                                int* __restrict__ rowlen,
                                                float* __restrict__ dinv) {
    __shared__ float tile[64][65];
    int b = blockIdx.x, t = threadIdx.x;
    if (b < 4096) {
        size_t idx = ((size_t)b * 256 + t) * 4;
        int row = (int)(idx >> 10);
        int col = (int)(idx & 1023);
        float4 v = *(const float4*)(x + idx);
        ushort h0 = f2bf(v.x), h1 = f2bf(v.y), h2 = f2bf(v.z), h3 = f2bf(v.w);
        short4 h = make_short4((short)h0, (short)h1, (short)h2, (short)h3);
        short4 l = make_short4((short)f2bf(v.x - bf2f(h0)), (short)f2bf(v.y - bf2f(h1)),
                               (short)f2bf(v.z - bf2f(h2)), (short)f2bf(v.w - bf2f(h3)));
        short* rp = x3 + (size_t)row * 3072 + col;
        *(short4*)(rp)        = h;
        *(short4*)(rp + 1024) = l;
        *(short4*)(rp + 2048) = h;
        return;
    }
    if (b < 4232) {
        const float* W; short* B3; int K, head, kb;
        if (b < 4224) { int id = b - 4096; W = Whd; B3 = W3;  K = 1024; head = id >> 4; kb = id & 15; }
        else          { int id = b - 4224; W = Wo;  B3 = W23; K = 512;  head = 0;       kb = id; }
        int k0 = kb * 64;
        const float* src = W + (size_t)head * K * 64 + (size_t)k0 * 64;
#pragma unroll
        for (int i = 0; i < 16; i++) {
            int lin = t + i * 256;
            int kk = lin >> 6, nn = lin & 63;
            tile[nn][kk] = src[kk * 64 + nn];
        }
        __syncthreads();
#pragma unroll
        for (int i = 0; i < 16; i++) {
            int lin = t + i * 256;
            int nn = lin >> 6, kk = lin & 63;
            float v = tile[nn][kk];
            ushort h = f2bf(v);
            ushort l = f2bf(v - bf2f(h));
            short* rp = B3 + (size_t)(head * 64 + nn) * (3 * (size_t)K) + k0 + kk;
            rp[0]     = (short)h;
            rp[K]     = (short)h;
            rp[2 * K] = (short)l;
        }
        return;
    }
    // CSR build: one row per wave
    int wid = t >> 6, lane = t & 63;
    int row = (b - 4232) * 4 + wid;
    const int4* arow = (const int4*)(adj + (size_t)row * N_NODES);
    unsigned long long pre = (1ull << lane) - 1ull;
    int count = 0;
    ushort* crow = csr + (size_t)row * MAXDEG;
    for (int blk = 0; blk < N_NODES / 256; blk++) {
        int4 v = arow[blk * 64 + lane];
        unsigned long long m0 = __ballot(v.x != 0);
        unsigned long long m1 = __ballot(v.y != 0);
        unsigned long long m2 = __ballot(v.z != 0);
        unsigned long long m3 = __ballot(v.w != 0);
        int pos = count + __popcll(m0 & pre) + __popcll(m1 & pre)
                        + __popcll(m2 & pre) + __popcll(m3 & pre);
        int base = blk * 256 + lane * 4;
        if (v.x) { if (pos < MAXDEG) crow[pos] = (ushort)base;       pos++; }
        if (v.y) { if (pos < MAXDEG) crow[pos] = (ushort)(base + 1); pos++; }
        if (v.z) { if (pos < MAXDEG) crow[pos] = (ushort)(base + 2); pos++; }
        if (v.w) { if (pos < MAXDEG) crow[pos] = (ushort)(base + 3); pos++; }
        count += __popcll(m0) + __popcll(m1) + __popcll(m2) + __popcll(m3);
    }
    if (lane == 0) {
        rowlen[row] = count < MAXDEG ? count : MAXDEG;
        dinv[row] = 1.0f / sqrtf((float)count);
    }
}

// ---------------------------------------------------------------------------
// K2: gemm1, m97-structure. C = A[4096][3072] @ B[512][3072]^T, head-major
// output + fused f1/f2 epilogue. Tile 128x64, BK=64, 4 waves (2x2), wave
// tile 64x32 (MR=4,NR=2). Staging via global_load_lds width=16 into LINEAR
// LDS (no pad - required by gload_lds), double-buffered, 1 barrier/K-step.
// Grid 256 (32x8 XCD-swizzled).
// ---------------------------------------------------------------------------
__global__ __launch_bounds__(256) void gemm1_m97(const short* __restrict__ A,
                                                 const short* __restrict__ B,
                                                 float* __restrict__ C,
                                                 const float* __restrict__ aH,
                                                 float* __restrict__ f1h,
                                                 float* __restrict__ f2h) {
    __shared__ __align__(16) short As[2][128 * 64];   // 16 KB x2
    __shared__ __align__(16) short Bs[2][64 * 64];    // 8 KB x2
    __shared__ float f1p[2][128], f2p[2][128];

    int tid = threadIdx.x, lane = tid & 63, wid = tid >> 6;
    int wr = wid >> 1, wc = wid & 1;
    int lin = blockIdx.x;
    int bx = (lin & 7) * 4 + (lin >> 6);    // 0..31
    int by = (lin >> 3) & 7;                // 0..7 == head
    int row0 = bx * 128, col0 = by * 64;
    const int Kp = 3072;

    int sRow = lane >> 3;          // 0..7 within chunk
    int sCol = (lane & 7) * 8;     // shorts

    auto STAGE = [&](int buf, int k0) {
#pragma unroll
        for (int c = 0; c < 4; c++) {
            int q = c * 4 + wid;   // 0..15
            const short* gp = A + (size_t)(row0 + 8 * q + sRow) * Kp + k0 + sCol;
            __builtin_amdgcn_global_load_lds(
                (const __attribute__((address_space(1))) void*)gp,
                (__attribute__((address_space(3))) void*)&As[buf][q * 512], 16, 0, 0);
        }
#pragma unroll
        for (int c = 0; c < 2; c++) {
            int q = c * 4 + wid;   // 0..7
            const short* gp = B + (size_t)(col0 + 8 * q + sRow) * Kp + k0 + sCol;
            __builtin_amdgcn_global_load_lds(
                (const __attribute__((address_space(1))) void*)gp,
                (__attribute__((address_space(3))) void*)&Bs[buf][q * 512], 16, 0, 0);
        }
    };

    f32x4 acc[4][2];
#pragma unroll
    for (int m = 0; m < 4; m++)
#pragma unroll
        for (int n = 0; n < 2; n++) acc[m][n] = (f32x4){0.f, 0.f, 0.f, 0.f};

    STAGE(0, 0);
    __syncthreads();

    const int nt = 48;   // 3072/64
    for (int t = 0; t < nt; ++t) {
        int cur = t & 1;
        if (t + 1 < nt) STAGE(cur ^ 1, (t + 1) * 64);
#pragma unroll
        for (int ks = 0; ks < 2; ++ks) {
            short8 ah[4], bh[2];
            int ko = ks * 32 + (lane >> 4) * 8;
#pragma unroll
            for (int m = 0; m < 4; m++)
                ah[m] = *(const short8*)&As[cur][(wr * 64 + m * 16 + (lane & 15)) * 64 + ko];
#pragma unroll
            for (int n = 0; n < 2; n++)
                bh[n] = *(const short8*)&Bs[cur][(wc * 32 + n * 16 + (lane & 15)) * 64 + ko];
#pragma unroll
            for (int m = 0; m < 4; m++)
#pragma unroll
                for (int n = 0; n < 2; n++)
                    acc[m][n] = __builtin_amdgcn_mfma_f32_16x16x32_bf16(ah[m], bh[n], acc[m][n], 0, 0, 0);
        }
        __syncthreads();   // drains stage (vmcnt) + frag reads
    }

    // head-major C write: head == by
#pragma unroll
    for (int m = 0; m < 4; m++)
#pragma unroll
        for (int n = 0; n < 2; n++)
#pragma unroll
            for (int r = 0; r < 4; r++) {
                int rr = row0 + wr * 64 + m * 16 + (lane >> 4) * 4 + r;
                int cc = wc * 32 + n * 16 + (lane & 15);
                C[(size_t)by * (N_NODES * 64) + (size_t)rr * 64 + cc] = acc[m][n][r];
            }

    // fused f1/f2 epilogue
    const float* ahp = aH + by * 128;
    int cl = lane & 15;
    float a1x = ahp[wc * 32 + cl],      a1y = ahp[wc * 32 + 16 + cl];
    float a2x = ahp[64 + wc * 32 + cl], a2y = ahp[64 + wc * 32 + 16 + cl];
#pragma unroll
    for (int m = 0; m < 4; m++)
#pragma unroll
        for (int r = 0; r < 4; r++) {
            float s1 = acc[m][0][r] * a1x + acc[m][1][r] * a1y;
            float s2 = acc[m][0][r] * a2x + acc[m][1][r] * a2y;
#pragma unroll
            for (int off = 1; off < 16; off <<= 1) {
                s1 += __shfl_xor(s1, off);
                s2 += __shfl_xor(s2, off);
            }
            if ((lane & 15) == 0) {
                int rl = wr * 64 + m * 16 + (lane >> 4) * 4 + r;
                f1p[wc][rl] = s1;
                f2p[wc][rl] = s2;
            }
        }
    __syncthreads();
    if (tid < 128) {
        f1h[(size_t)by * N_NODES + row0 + tid] = f1p[0][tid] + f1p[1][tid];
        f2h[(size_t)by * N_NODES + row0 + tid] = f2p[0][tid] + f2p[1][tid];
    }
}

// ---------------------------------------------------------------------------
// K3: gemm2 (reg-staged, concat-K). Tile 64x64, BK=128, split-K via z.
// ---------------------------------------------------------------------------
#define GBM 64
#define GBN 64
#define GBK 128
#define LDK 136

__global__ __launch_bounds__(256, 2) void gemm_mfma(const short* __restrict__ A,
                                                    const short* __restrict__ B,
                                                    float* __restrict__ C,
                                                    int Kp, int kChunk, int cPartStride) {
    __shared__ __align__(16) short As[2][GBM * LDK];
    __shared__ __align__(16) short Bs[2][GBN * LDK];

    int tid = threadIdx.x, lane = tid & 63, wid = tid >> 6;
    int wr = wid >> 1, wc = wid & 1;
    int row0 = blockIdx.x * GBM, col0 = blockIdx.y * GBN;
    int kbase = blockIdx.z * kChunk;
    C += (size_t)blockIdx.z * cPartStride;

    int aRow[4], aKc[4];
#pragma unroll
    for (int c = 0; c < 4; c++) {
        int lin = tid + c * 256;
        aRow[c] = lin >> 4; aKc[c] = (lin & 15) * 8;
    }

    short8 rA[4], rB[4];
    auto LOAD = [&](int k0) {
#pragma unroll
        for (int c = 0; c < 4; c++) {
            rA[c] = *(const short8*)(A + (size_t)(row0 + aRow[c]) * Kp + kbase + k0 + aKc[c]);
            rB[c] = *(const short8*)(B + (size_t)(col0 + aRow[c]) * Kp + kbase + k0 + aKc[c]);
        }
    };
    auto WRITE = [&](int buf) {
#pragma unroll
        for (int c = 0; c < 4; c++) {
            *(short8*)&As[buf][aRow[c] * LDK + aKc[c]] = rA[c];
            *(short8*)&Bs[buf][aRow[c] * LDK + aKc[c]] = rB[c];
        }
    };

    f32x4 acc[2][2];
#pragma unroll
    for (int m = 0; m < 2; m++)
#pragma unroll
        for (int n = 0; n < 2; n++) acc[m][n] = (f32x4){0.f, 0.f, 0.f, 0.f};

    LOAD(0);
    WRITE(0);
    __syncthreads();

    int nt = kChunk / GBK;
    for (int t = 0; t < nt; ++t) {
        int cur = t & 1;
        if (t + 1 < nt) LOAD((t + 1) * GBK);
#pragma unroll
        for (int ks = 0; ks < GBK / 32; ++ks) {
            short8 ah[2], bh[2];
            int ko = ks * 32 + (lane >> 4) * 8;
#pragma unroll
            for (int m = 0; m < 2; m++)
                ah[m] = *(const short8*)&As[cur][(wr * 32 + m * 16 + (lane & 15)) * LDK + ko];
#pragma unroll
            for (int n = 0; n < 2; n++)
                bh[n] = *(const short8*)&Bs[cur][(wc * 32 + n * 16 + (lane & 15)) * LDK + ko];
#pragma unroll
            for (int m = 0; m < 2; m++)
#pragma unroll
                for (int n = 0; n < 2; n++)
                    acc[m][n] = __builtin_amdgcn_mfma_f32_16x16x32_bf16(ah[m], bh[n], acc[m][n], 0, 0, 0);
        }
        if (t + 1 < nt) WRITE(cur ^ 1);
        __syncthreads();
    }

#pragma unroll
    for (int m = 0; m < 2; m++)
#pragma unroll
        for (int n = 0; n < 2; n++)
#pragma unroll
            for (int r = 0; r < 4; r++) {
                int rr = row0 + wr * 32 + m * 16 + (lane >> 4) * 4 + r;
                int cc = col0 + wc * 32 + n * 16 + (lane & 15);
                C[(size_t)rr * 64 + cc] = acc[m][n][r];
            }
}

// ---------------------------------------------------------------------------
// K4: attn layer 1. 512 threads = 8 waves; each wave owns TWO rows of ONE
// head (amortizes softmax serial phases, doubles independent load streams).
// head = blockIdx&7 (XCD pinning); f2 staged to LDS.
// ---------------------------------------------------------------------------
__global__ __launch_bounds__(512, 4) void attn1(const float* __restrict__ Whh,
                                                const float* __restrict__ f1h,
                                                const float* __restrict__ f2h,
                                                const ushort* __restrict__ csr,
                                                const int* __restrict__ rowlen,
                                                short* __restrict__ hp3) {
    __shared__ float  f2s[N_NODES];        // 16 KB
    __shared__ float  w[16][MAXDEG];       // 16 KB
    __shared__ ushort cols[16][MAXDEG];    // 8 KB
    int lin = blockIdx.x;
    int h = lin & 7;
    int wid = threadIdx.x >> 6, lane = threadIdx.x & 63;
    int i0 = (lin >> 3) * 16 + wid * 2;    // rows i0, i0+1
    int sA = wid * 2, sB = sA + 1;

    {   // stage f2 for this head
        const float4* f2g = (const float4*)(f2h + (size_t)h * N_NODES);
        float4 v0 = f2g[threadIdx.x];
        float4 v1 = f2g[threadIdx.x + 512];
        *(float4*)&f2s[threadIdx.x * 4] = v0;
        *(float4*)&f2s[(threadIdx.x + 512) * 4] = v1;
    }
    __syncthreads();

    float sinvR[2];
    int lenR[2];
#pragma unroll
    for (int r = 0; r < 2; r++) {
        int i = i0 + r, slot = sA + r;
        int len = rowlen[i];
        lenR[r] = len;
        const ushort* crow = csr + (size_t)i * MAXDEG;
        float f1v = f1h[(size_t)h * N_NODES + i];
        float ev[4]; int cv[4];
        float m = -1e30f;
#pragma unroll
        for (int c = 0; c < 4; c++) {
            int k = lane + c * 64;
            if (k < len) {
                int j = crow[k];
                float e = f1v + f2s[j];
                e = e > 0.f ? e : ALPHA * e;
                ev[c] = e; cv[c] = j;
                m = fmaxf(m, e);
            }
        }
#pragma unroll
        for (int off = 32; off; off >>= 1) m = fmaxf(m, __shfl_xor(m, off));
        float s = 0.f;
#pragma unroll
        for (int c = 0; c < 4; c++) {
            int k = lane + c * 64;
            if (k < len) {
                float ex = __expf(ev[c] - m);
                s += ex;
                w[slot][k] = ex;
                cols[slot][k] = (ushort)cv[c];
            }
        }
#pragma unroll
        for (int off = 32; off; off >>= 1) s += __shfl_xor(s, off);
        sinvR[r] = 1.0f / s;
    }

    // pad both rows to the common multiple-of-8 length
    int lc = lenR[0] > lenR[1] ? lenR[0] : lenR[1];
    int len8 = (lc + 7) & ~7;
    for (int k = lenR[0] + lane; k < len8; k += 64) { w[sA][k] = 0.f; cols[sA][k] = 0; }
    for (int k = lenR[1] + lane; k < len8; k += 64) { w[sB][k] = 0.f; cols[sB][k] = 0; }

    int q = lane >> 4, d = lane & 15;
    const float4* base = (const float4*)(Whh + (size_t)h * (N_NODES * 64)) + d;
    f32x4 A0 = {0.f,0.f,0.f,0.f}, A1 = A0, B0 = A0, B1 = A0;
    for (int k = 0; k < len8; k += 8) {
        int   ja0 = cols[sA][k + q];      float wa0 = w[sA][k + q];
        int   ja1 = cols[sA][k + 4 + q];  float wa1 = w[sA][k + 4 + q];
        int   jb0 = cols[sB][k + q];      float wb0 = w[sB][k + q];
        int   jb1 = cols[sB][k + 4 + q];  float wb1 = w[sB][k + 4 + q];
        float4 va0 = base[(size_t)ja0 * 16];
        float4 va1 = base[(size_t)ja1 * 16];
        float4 vb0 = base[(size_t)jb0 * 16];
        float4 vb1 = base[(size_t)jb1 * 16];
        A0[0] += wa0 * va0.x; A0[1] += wa0 * va0.y; A0[2] += wa0 * va0.z; A0[3] += wa0 * va0.w;
        A1[0] += wa1 * va1.x; A1[1] += wa1 * va1.y; A1[2] += wa1 * va1.z; A1[3] += wa1 * va1.w;
        B0[0] += wb0 * vb0.x; B0[1] += wb0 * vb0.y; B0[2] += wb0 * vb0.z; B0[3] += wb0 * vb0.w;
        B1[0] += wb1 * vb1.x; B1[1] += wb1 * vb1.y; B1[2] += wb1 * vb1.z; B1[3] += wb1 * vb1.w;
    }

#pragma unroll
    for (int r = 0; r < 2; r++) {
        f32x4 R;
        if (r == 0) { R[0]=A0[0]+A1[0]; R[1]=A0[1]+A1[1]; R[2]=A0[2]+A1[2]; R[3]=A0[3]+A1[3]; }
        else        { R[0]=B0[0]+B1[0]; R[1]=B0[1]+B1[1]; R[2]=B0[2]+B1[2]; R[3]=B0[3]+B1[3]; }
        float rx = R[0], ry = R[1], rz = R[2], rw = R[3];
#pragma unroll
        for (int off = 16; off <= 32; off <<= 1) {
            rx += __shfl_xor(rx, off);
            ry += __shfl_xor(ry, off);
            rz += __shfl_xor(rz, off);
            rw += __shfl_xor(rw, off);
        }
        if (lane < 16) {
            float sinv = sinvR[r];
            float v[4] = {rx * sinv, ry * sinv, rz * sinv, rw * sinv};
            short hi[4], lo[4];
#pragma unroll
            for (int c = 0; c < 4; c++) {
                float e = v[c] > 0.f ? v[c] : __expf(v[c]) - 1.f;   // ELU
                ushort hh = f2bf(e);
                hi[c] = (short)hh;
                lo[c] = (short)f2bf(e - bf2f(hh));
            }
            short* rp = hp3 + (size_t)(i0 + r) * 1536 + h * 64 + d * 4;
            *(short4*)(rp)        = make_short4(hi[0], hi[1], hi[2], hi[3]);
            *(short4*)(rp + 512)  = make_short4(lo[0], lo[1], lo[2], lo[3]);
            *(short4*)(rp + 1024) = make_short4(hi[0], hi[1], hi[2], hi[3]);
        }
    }
}

// ---------------------------------------------------------------------------
// K5: sum gemm2 split-K partials -> Wh2, compute f1o/f2o. 4 rows/block.
// ---------------------------------------------------------------------------
__global__ __launch_bounds__(256) void f2sum(const float* __restrict__ part,
                                             const float* __restrict__ a,
                                             float* __restrict__ Wh2,
                                             float* __restrict__ f1o,
                                             float* __restrict__ f2o) {
    int wid = threadIdx.x >> 6, l = threadIdx.x & 63;
    int i = blockIdx.x * 4 + wid;
    size_t o = (size_t)i * 64 + l;
    const size_t S = (size_t)N_NODES * 64;
    float v = part[o] + part[o + S] + part[o + 2 * S] + part[o + 3 * S];
    Wh2[o] = v;
    float p1 = v * a[l], p2 = v * a[64 + l];
#pragma unroll
    for (int off = 32; off; off >>= 1) {
        p1 += __shfl_xor(p1, off);
        p2 += __shfl_xor(p2, off);
    }
    if (l == 0) { f1o[i] = p1; f2o[i] = p2; }
}

// ---------------------------------------------------------------------------
// K6: attn layer 2 + first GCN matmul; f2o staged to LDS; out pre-scaled.
// ---------------------------------------------------------------------------
__global__ __launch_bounds__(256, 6) void attn2_g0(const float* __restrict__ Wh2,
                                                   const float* __restrict__ f1o,
                                                   const float* __restrict__ f2o,
                                                   const ushort* __restrict__ csr,
                                                   const int* __restrict__ rowlen,
                                                   const float* __restrict__ W0,
                                                   const float* __restrict__ dinv,
                                                   float* __restrict__ t0) {
    __shared__ float  f2s[N_NODES];      // 16 KB
    __shared__ float  w[4][MAXDEG];
    __shared__ ushort cl[4][MAXDEG];
    __shared__ float  hrow[4][64];
    int wid = threadIdx.x >> 6, lane = threadIdx.x & 63;
    int i = blockIdx.x * 4 + wid;

    {
        const float4* f2g = (const float4*)f2o;
#pragma unroll
        for (int c = 0; c < 4; c++) {
            int idx = threadIdx.x + c * 256;
            *(float4*)&f2s[idx * 4] = f2g[idx];
        }
    }
    __syncthreads();

    int len = rowlen[i];
    const ushort* crow = csr + (size_t)i * MAXDEG;
    float myf1 = f1o[i];

    float ev[4]; int cv[4];
    float m = -1e30f;
#pragma unroll
    for (int c = 0; c < 4; c++) {
        int k = lane + c * 64;
        if (k < len) {
            int j = crow[k];
            float e = myf1 + f2s[j];
            e = e > 0.f ? e : ALPHA * e;
            ev[c] = e; cv[c] = j;
            m = fmaxf(m, e);
        }
    }
#pragma unroll
    for (int off = 32; off; off >>= 1) m = fmaxf(m, __shfl_xor(m, off));
    float s = 0.f;
#pragma unroll
    for (int c = 0; c < 4; c++) {
        int k = lane + c * 64;
        if (k < len) {
            float ex = __expf(ev[c] - m);
            s += ex;
            w[wid][k] = ex;
            cl[wid][k] = (ushort)cv[c];
        }
    }
#pragma unroll
    for (int off = 32; off; off >>= 1) s += __shfl_xor(s, off);
    float sinv = 1.0f / s;

    int len16 = (len + 15) & ~15;
    if (lane < len16 - len) {
        w[wid][len + lane] = 0.f;
        cl[wid][len + lane] = 0;
    }

    int q = lane >> 4, d = lane & 15;
    const float4* base = (const float4*)Wh2 + d;
    f32x4 A0 = {0.f,0.f,0.f,0.f}, A1 = A0, A2 = A0, A3 = A0;
    for (int k = 0; k < len16; k += 16) {
        int   j0 = cl[wid][k + q];       float w0 = w[wid][k + q];
        int   j1 = cl[wid][k + 4 + q];   float w1 = w[wid][k + 4 + q];
        int   j2 = cl[wid][k + 8 + q];   float w2 = w[wid][k + 8 + q];
        int   j3 = cl[wid][k + 12 + q];  float w3 = w[wid][k + 12 + q];
        float4 v0 = base[(size_t)j0 * 16];
        float4 v1 = base[(size_t)j1 * 16];
        float4 v2 = base[(size_t)j2 * 16];
        float4 v3 = base[(size_t)j3 * 16];
        A0[0] += w0 * v0.x; A0[1] += w0 * v0.y; A0[2] += w0 * v0.z; A0[3] += w0 * v0.w;
        A1[0] += w1 * v1.x; A1[1] += w1 * v1.y; A1[2] += w1 * v1.z; A1[3] += w1 * v1.w;
        A2[0] += w2 * v2.x; A2[1] += w2 * v2.y; A2[2] += w2 * v2.z; A2[3] += w2 * v2.w;
        A3[0] += w3 * v3.x; A3[1] += w3 * v3.y; A3[2] += w3 * v3.z; A3[3] += w3 * v3.w;
    }
    float rx = (A0[0] + A1[0]) + (A2[0] + A3[0]);
    float ry = (A0[1] + A1[1]) + (A2[1] + A3[1]);
    float rz = (A0[2] + A1[2]) + (A2[2] + A3[2]);
    float rw = (A0[3] + A1[3]) + (A2[3] + A3[3]);
#pragma unroll
    for (int off = 16; off <= 32; off <<= 1) {
        rx += __shfl_xor(rx, off);
        ry += __shfl_xor(ry, off);
        rz += __shfl_xor(rz, off);
        rw += __shfl_xor(rw, off);
    }
    if (lane < 16) {
        float4 r = make_float4(rx * sinv, ry * sinv, rz * sinv, rw * sinv);
        *(float4*)&hrow[wid][d * 4] = r;
    }

    float ox = 0.f, oy = 0.f, oz = 0.f, ow = 0.f;
#pragma unroll
    for (int it = 0; it < 16; it++) {
        int kk = q * 16 + it;
        float hv = hrow[wid][kk];
        float4 wv = *(const float4*)(W0 + kk * 64 + d * 4);
        ox += hv * wv.x; oy += hv * wv.y; oz += hv * wv.z; ow += hv * wv.w;
    }
#pragma unroll
    for (int off = 16; off <= 32; off <<= 1) {
        ox += __shfl_xor(ox, off);
        oy += __shfl_xor(oy, off);
        oz += __shfl_xor(oz, off);
        ow += __shfl_xor(ow, off);
    }
    if (lane < 16) {
        float di = dinv[i];
        *(float4*)(t0 + (size_t)i * 64 + d * 4) =
            make_float4(ox * di, oy * di, oz * di, ow * di);
    }
}

// ---------------------------------------------------------------------------
// K7: GCN step: h = relu(dinv_i * sum t'_j); out = dinv_i * (h @ W).
// ---------------------------------------------------------------------------
__global__ __launch_bounds__(256, 6) void spmv_gemm(const float* __restrict__ t,
                                                    const ushort* __restrict__ csr,
                                                    const int* __restrict__ rowlen,
                                                    const float* __restrict__ W,
                                                    const float* __restrict__ dinv,
                                                    float* __restrict__ out) {
    __shared__ float hrow[4][64];
    int wid = threadIdx.x >> 6, lane = threadIdx.x & 63;
    int i = blockIdx.x * 4 + wid;
    int len = rowlen[i];
    const ushort* ci = csr + (size_t)i * MAXDEG;
    int q = lane >> 4, d = lane & 15;
    const float4* base = (const float4*)t + d;
    int len16 = (len + 15) & ~15;
    f32x4 A0 = {0.f,0.f,0.f,0.f}, A1 = A0, A2 = A0, A3 = A0;
    for (int k = 0; k < len16; k += 16) {
        int k0 = k + q, k1 = k + 4 + q, k2 = k + 8 + q, k3 = k + 12 + q;
        float m0 = k0 < len ? 1.f : 0.f;
        float m1 = k1 < len ? 1.f : 0.f;
        float m2 = k2 < len ? 1.f : 0.f;
        float m3 = k3 < len ? 1.f : 0.f;
        int j0 = ci[k0 < len ? k0 : 0];
        int j1 = ci[k1 < len ? k1 : 0];
        int j2 = ci[k2 < len ? k2 : 0];
        int j3 = ci[k3 < len ? k3 : 0];
        float4 v0 = base[(size_t)j0 * 16];
        float4 v1 = base[(size_t)j1 * 16];
        float4 v2 = base[(size_t)j2 * 16];
        float4 v3 = base[(size_t)j3 * 16];
        A0[0] += m0 * v0.x; A0[1] += m0 * v0.y; A0[2] += m0 * v0.z; A0[3] += m0 * v0.w;
        A1[0] += m1 * v1.x; A1[1] += m1 * v1.y; A1[2] += m1 * v1.z; A1[3] += m1 * v1.w;
        A2[0] += m2 * v2.x; A2[1] += m2 * v2.y; A2[2] += m2 * v2.z; A2[3] += m2 * v2.w;
        A3[0] += m3 * v3.x; A3[1] += m3 * v3.y; A3[2] += m3 * v3.z; A3[3] += m3 * v3.w;
    }
    float rx = (A0[0] + A1[0]) + (A2[0] + A3[0]);
    float ry = (A0[1] + A1[1]) + (A2[1] + A3[1]);
    float rz = (A0[2] + A1[2]) + (A2[2] + A3[2]);
    float rw = (A0[3] + A1[3]) + (A2[3] + A3[3]);
#pragma unroll
    for (int off = 16; off <= 32; off <<= 1) {
        rx += __shfl_xor(rx, off);
        ry += __shfl_xor(ry, off);
        rz += __shfl_xor(rz, off);
        rw += __shfl_xor(rw, off);
    }
    float di = dinv[i];
    if (lane < 16) {
        float4 r = make_float4(fmaxf(rx * di, 0.f), fmaxf(ry * di, 0.f),
                               fmaxf(rz * di, 0.f), fmaxf(rw * di, 0.f));
        *(float4*)&hrow[wid][d * 4] = r;
    }

    float ox = 0.f, oy = 0.f, oz = 0.f, ow = 0.f;
#pragma unroll
    for (int it = 0; it < 16; it++) {
        int kk = q * 16 + it;
        float hv = hrow[wid][kk];
        float4 wv = *(const float4*)(W + kk * 64 + d * 4);
        ox += hv * wv.x; oy += hv * wv.y; oz += hv * wv.z; ow += hv * wv.w;
    }
#pragma unroll
    for (int off = 16; off <= 32; off <<= 1) {
        ox += __shfl_xor(ox, off);
        oy += __shfl_xor(oy, off);
        oz += __shfl_xor(oz, off);
        ow += __shfl_xor(ow, off);
    }
    if (lane < 16)
        *(float4*)(out + (size_t)i * 64 + d * 4) =
            make_float4(ox * di, oy * di, oz * di, ow * di);
}

// ---------------------------------------------------------------------------
// K8: final GCN step into classifier. Gather; 64x8 matmul.
// ---------------------------------------------------------------------------
__global__ __launch_bounds__(256, 4) void spmv_cls(const float* __restrict__ t,
                                                   const ushort* __restrict__ csr,
                                                   const int* __restrict__ rowlen,
                                                   const float* __restrict__ Wc,
                                                   const float* __restrict__ dinv,
                                                   float* __restrict__ t8) {
    __shared__ float hrow[4][64];
    int wid = threadIdx.x >> 6, lane = threadIdx.x & 63;
    int i = blockIdx.x * 4 + wid;
    int len = rowlen[i];
    const ushort* ci = csr + (size_t)i * MAXDEG;
    int q = lane >> 4, d = lane & 15;
    const float4* base = (const float4*)t + d;
    int len16 = (len + 15) & ~15;
    f32x4 A0 = {0.f,0.f,0.f,0.f}, A1 = A0, A2 = A0, A3 = A0;
    for (int k = 0; k < len16; k += 16) {
        int k0 = k + q, k1 = k + 4 + q, k2 = k + 8 + q, k3 = k + 12 + q;
        float m0 = k0 < len ? 1.f : 0.f;
        float m1 = k1 < len ? 1.f : 0.f;
        float m2 = k2 < len ? 1.f : 0.f;
        float m3 = k3 < len ? 1.f : 0.f;
        int j0 = ci[k0 < len ? k0 : 0];
        int j1 = ci[k1 < len ? k1 : 0];
        int j2 = ci[k2 < len ? k2 : 0];
        int j3 = ci[k3 < len ? k3 : 0];
        float4 v0 = base[(size_t)j0 * 16];
        float4 v1 = base[(size_t)j1 * 16];
        float4 v2 = base[(size_t)j2 * 16];
        float4 v3 = base[(size_t)j3 * 16];
        A0[0] += m0 * v0.x; A0[1] += m0 * v0.y; A0[2] += m0 * v0.z; A0[3] += m0 * v0.w;
        A1[0] += m1 * v1.x; A1[1] += m1 * v1.y; A1[2] += m1 * v1.z; A1[3] += m1 * v1.w;
        A2[0] += m2 * v2.x; A2[1] += m2 * v2.y; A2[2] += m2 * v2.z; A2[3] += m2 * v2.w;
        A3[0] += m3 * v3.x; A3[1] += m3 * v3.y; A3[2] += m3 * v3.z; A3[3] += m3 * v3.w;
    }
    float rx = (A0[0] + A1[0]) + (A2[0] + A3[0]);
    float ry = (A0[1] + A1[1]) + (A2[1] + A3[1]);
    float rz = (A0[2] + A1[2]) + (A2[2] + A3[2]);
    float rw = (A0[3] + A1[3]) + (A2[3] + A3[3]);
#pragma unroll
    for (int off = 16; off <= 32; off <<= 1) {
        rx += __shfl_xor(rx, off);
        ry += __shfl_xor(ry, off);
        rz += __shfl_xor(rz, off);
        rw += __shfl_xor(rw, off);
    }
    float di = dinv[i];
    if (lane < 16) {
        float4 r = make_float4(fmaxf(rx * di, 0.f), fmaxf(ry * di, 0.f),
                               fmaxf(rz * di, 0.f), fmaxf(rw * di, 0.f));
        *(float4*)&hrow[wid][d * 4] = r;
    }
    int col = lane & 7, k0s = (lane >> 3) * 8;
    float o = 0.f;
#pragma unroll
    for (int kk = 0; kk < 8; kk++) o += hrow[wid][k0s + kk] * Wc[(k0s + kk) * 8 + col];
    o += __shfl_down(o, 32);
    o += __shfl_down(o, 16);
    o += __shfl_down(o, 8);
    if (lane < 8) t8[(size_t)i * 8 + lane] = o * di;
}

// ---------------------------------------------------------------------------
// K9: final propagation on pre-scaled t8': out_i = dinv_i * sum t8'_j.
// ---------------------------------------------------------------------------
__global__ __launch_bounds__(256) void spmv8(const float* __restrict__ t8,
                                             const ushort* __restrict__ csr,
                                             const int* __restrict__ rowlen,
                                             const float* __restrict__ dinv,
                                             float* __restrict__ out) {
    int wid = threadIdx.x >> 6, lane = threadIdx.x & 63;
    int i = blockIdx.x * 4 + wid;
    int len = rowlen[i];
    const ushort* ci = csr + (size_t)i * MAXDEG;
    int col = lane & 7, chunk = lane >> 3;
    float acc = 0.f;
    for (int k = chunk; k < len; k += 8)
        acc += t8[(size_t)ci[k] * 8 + col];
    acc += __shfl_down(acc, 32);
    acc += __shfl_down(acc, 16);
    acc += __shfl_down(acc, 8);
    if (lane < 8) out[(size_t)i * 8 + lane] = acc * dinv[i];
}

// ---------------------------------------------------------------------------
extern "C" void kernel_launch(void* const* d_in, const int* in_sizes, int n_in,
                              void* d_out, int out_size, void* d_ws, size_t ws_size,
                              hipStream_t stream) {
    const float* x       = (const float*)d_in[0];
    const int*   adj     = (const int*)d_in[1];
    const float* W_heads = (const float*)d_in[2];
    const float* a_heads = (const float*)d_in[3];
    const float* W_out   = (const float*)d_in[4];
    const float* a_out   = (const float*)d_in[5];
    const float* W_gcn   = (const float*)d_in[6];
    const float* W_cls   = (const float*)d_in[7];
    float* outp = (float*)d_out;

    char* p = (char*)d_ws;
    short*  x3     = (short*)p;  p += (size_t)N_NODES * 3072 * 2;     // 25.2 MB
    short*  W3     = (short*)p;  p += (size_t)512 * 3072 * 2;         // 3.1 MB
    short*  W23    = (short*)p;  p += (size_t)64 * 1536 * 2;
    float*  Whh    = (float*)p;  p += (size_t)NHEADS * N_NODES * 64 * 4;  // 8 MB
    float*  f1h    = (float*)p;  p += (size_t)NHEADS * N_NODES * 4;
    float*  f2h    = (float*)p;  p += (size_t)NHEADS * N_NODES * 4;
    float*  Wh2    = (float*)p;  p += (size_t)N_NODES * 64 * 4;
    float*  f1o    = (float*)p;  p += (size_t)N_NODES * 4;
    float*  f2o    = (float*)p;  p += (size_t)N_NODES * 4;
    float*  tA     = (float*)p;  p += (size_t)N_NODES * 64 * 4;
    float*  tB     = (float*)p;  p += (size_t)N_NODES * 64 * 4;
    float*  t8     = (float*)p;  p += (size_t)N_NODES * 8 * 4;
    float*  dinv   = (float*)p;  p += (size_t)N_NODES * 4;
    int*    rowlen = (int*)p;    p += (size_t)N_NODES * 4;
    ushort* csr    = (ushort*)p; p += (size_t)N_NODES * MAXDEG * 2;   // 2 MB

    short* hp3  = x3;
    float* part = (float*)((char*)x3 + (16u << 20));

    // K1: prep (splits) + CSR build in one launch
    prep_all<<<4096 + 128 + 8 + 1024, 256, 0, stream>>>(
        x, adj, W_heads, W_out, x3, W3, W23, csr, rowlen, dinv);

    // K2: gemm1 (m97 structure) + fused f1/f2
    gemm1_m97<<<256, 256, 0, stream>>>(x3, W3, Whh, a_heads, f1h, f2h);

    // K3: attn layer 1 (+ELU), 2 rows/wave -> hp3 concat-K
    attn1<<<N_NODES * NHEADS / 16, 512, 0, stream>>>(Whh, f1h, f2h, csr, rowlen, hp3);

    // K4: gemm2 partials = hp' @ W2' (K'=1536, split-K=4)
    gemm_mfma<<<dim3(N_NODES / GBM, 1, 4), 256, 0, stream>>>(
        hp3, W23, part, 1536, 384, N_NODES * 64);

    // K5: partial sum + f1o/f2o
    f2sum<<<N_NODES / 4, 256, 0, stream>>>(part, a_out, Wh2, f1o, f2o);

    // K6: attn layer 2 + W_gcn[0]
    attn2_g0<<<N_NODES / 4, 256, 0, stream>>>(Wh2, f1o, f2o, csr, rowlen, W_gcn, dinv, tA);

    // K7-8: GCN blocks 1,2
    spmv_gemm<<<N_NODES / 4, 256, 0, stream>>>(tA, csr, rowlen, W_gcn + 4096, dinv, tB);
    spmv_gemm<<<N_NODES / 4, 256, 0, stream>>>(tB, csr, rowlen, W_gcn + 8192, dinv, tA);

    // K9-10: final block + classifier, last propagation
    spmv_cls<<<N_NODES / 4, 256, 0, stream>>>(tA, csr, rowlen, W_cls, dinv, t8);
    spmv8<<<N_NODES / 4, 256, 0, stream>>>(t8, csr, rowlen, dinv, outp);
}

// Round 10
// 234.356 us; speedup vs baseline: 1.1753x; 1.1753x over previous
//
#include <hip/hip_runtime.h>
#include <hip/hip_bf16.h>
#include <math.h>

#define N_NODES 4096
#define NFEAT   1024
#define NHEADS  8
#define ALPHA   0.1f
#define MAXDEG  256

typedef short short8 __attribute__((ext_vector_type(8)));
typedef float f32x4  __attribute__((ext_vector_type(4)));

__device__ __forceinline__ ushort f2bf(float f) {
    uint b = __float_as_uint(f);
    b += 0x7FFFu + ((b >> 16) & 1u);            // RNE
    return (ushort)(b >> 16);
}
__device__ __forceinline__ float bf2f(ushort u) {
    return __uint_as_float(((uint)u) << 16);
}

// ---------------------------------------------------------------------------
// K1: merged prep. [0,4096): x -> x_h/x_l bf16. [4096,4224): W_heads
// transpose/split -> W3h/W3l [512][1024]. [4224,4232): W_out -> W2h/W2l
// [64][512]. [4232,5256): CSR (ushort) + dinv.
// ---------------------------------------------------------------------------
__global__ __launch_bounds__(256) void prep_all(const float* __restrict__ x,
                                                const int* __restrict__ adj,
                                                const float* __restrict__ Whd,
                                                const float* __restrict__ Wo,
                                                short* __restrict__ x_h,
                                                short* __restrict__ x_l,
                                                short* __restrict__ W3h,
                                                short* __restrict__ W3l,
                                                short* __restrict__ W2h,
                                                short* __restrict__ W2l,
                                                ushort* __restrict__ csr,
                                                int* __restrict__ rowlen,
                                                float* __restrict__ dinv) {
    __shared__ float tile[64][65];
    int b = blockIdx.x, t = threadIdx.x;
    if (b < 4096) {
        size_t idx = ((size_t)b * 256 + t) * 4;
        float4 v = *(const float4*)(x + idx);
        ushort h0 = f2bf(v.x), h1 = f2bf(v.y), h2 = f2bf(v.z), h3 = f2bf(v.w);
        short4 h = make_short4((short)h0, (short)h1, (short)h2, (short)h3);
        short4 l = make_short4((short)f2bf(v.x - bf2f(h0)), (short)f2bf(v.y - bf2f(h1)),
                               (short)f2bf(v.z - bf2f(h2)), (short)f2bf(v.w - bf2f(h3)));
        *(short4*)(x_h + idx) = h;
        *(short4*)(x_l + idx) = l;
        return;
    }
    if (b < 4232) {
        const float* W; short* Bh; short* Bl; int K, head, kb;
        if (b < 4224) { int id = b - 4096; W = Whd; Bh = W3h; Bl = W3l; K = 1024; head = id >> 4; kb = id & 15; }
        else          { int id = b - 4224; W = Wo;  Bh = W2h; Bl = W2l; K = 512;  head = 0;       kb = id; }
        int k0 = kb * 64;
        const float* src = W + (size_t)head * K * 64 + (size_t)k0 * 64;
#pragma unroll
        for (int i = 0; i < 16; i++) {
            int lin = t + i * 256;
            int kk = lin >> 6, nn = lin & 63;
            tile[nn][kk] = src[kk * 64 + nn];
        }
        __syncthreads();
#pragma unroll
        for (int i = 0; i < 16; i++) {
            int lin = t + i * 256;
            int nn = lin >> 6, kk = lin & 63;
            float v = tile[nn][kk];
            ushort h = f2bf(v);
            ushort l = f2bf(v - bf2f(h));
            size_t o = (size_t)(head * 64 + nn) * K + k0 + kk;
            Bh[o] = (short)h;
            Bl[o] = (short)l;
        }
        return;
    }
    // CSR build: one row per wave
    int wid = t >> 6, lane = t & 63;
    int row = (b - 4232) * 4 + wid;
    const int4* arow = (const int4*)(adj + (size_t)row * N_NODES);
    unsigned long long pre = (1ull << lane) - 1ull;
    int count = 0;
    ushort* crow = csr + (size_t)row * MAXDEG;
    for (int blk = 0; blk < N_NODES / 256; blk++) {
        int4 v = arow[blk * 64 + lane];
        unsigned long long m0 = __ballot(v.x != 0);
        unsigned long long m1 = __ballot(v.y != 0);
        unsigned long long m2 = __ballot(v.z != 0);
        unsigned long long m3 = __ballot(v.w != 0);
        int pos = count + __popcll(m0 & pre) + __popcll(m1 & pre)
                        + __popcll(m2 & pre) + __popcll(m3 & pre);
        int base = blk * 256 + lane * 4;
        if (v.x) { if (pos < MAXDEG) crow[pos] = (ushort)base;       pos++; }
        if (v.y) { if (pos < MAXDEG) crow[pos] = (ushort)(base + 1); pos++; }
        if (v.z) { if (pos < MAXDEG) crow[pos] = (ushort)(base + 2); pos++; }
        if (v.w) { if (pos < MAXDEG) crow[pos] = (ushort)(base + 3); pos++; }
        count += __popcll(m0) + __popcll(m1) + __popcll(m2) + __popcll(m3);
    }
    if (lane == 0) {
        rowlen[row] = count < MAXDEG ? count : MAXDEG;
        dinv[row] = 1.0f / sqrtf((float)count);
    }
}

// ---------------------------------------------------------------------------
// K2: bf16x3 MFMA GEMM, 4-array form: C = (Ah+Al)@(Bh+Bl)^T with 3 MFMAs
// per fragment pair (AhBh + AhBl + AlBh). Tile 64x64, BK=64, 4 waves (2x2),
// wave tile 32x32. LDS 72 KB padded (LDK=72 -> conflict-free) -> 2 blocks/CU.
// Reg-staged double buffer. headmajor + fused f1/f2 epilogue for gemm1.
// ---------------------------------------------------------------------------
#define GBM 64
#define GBN 64
#define GBK 64
#define LDK 72

__global__ __launch_bounds__(256, 2) void gemm3(const short* __restrict__ Ah,
                                                const short* __restrict__ Al,
                                                const short* __restrict__ Bh,
                                                const short* __restrict__ Bl,
                                                float* __restrict__ C,
                                                int Kp, int kChunk, int cPartStride,
                                                int swz, int headmajor,
                                                const float* __restrict__ aH,
                                                float* __restrict__ f1h,
                                                float* __restrict__ f2h) {
    __shared__ __align__(16) short Ash[2][GBM * LDK];
    __shared__ __align__(16) short Asl[2][GBM * LDK];
    __shared__ __align__(16) short Bsh[2][GBN * LDK];
    __shared__ __align__(16) short Bsl[2][GBN * LDK];

    int tid = threadIdx.x, lane = tid & 63, wid = tid >> 6;
    int wr = wid >> 1, wc = wid & 1;
    int bx, by;
    if (swz) {          // 512 blocks: bx = (lin&7)*8 + (lin>>6), by = (lin>>3)&7
        int lin = blockIdx.x;
        bx = (lin & 7) * 8 + (lin >> 6);
        by = (lin >> 3) & 7;
    } else {
        bx = blockIdx.x; by = blockIdx.y;
    }
    int row0 = bx * GBM, col0 = by * GBN;
    int kbase = blockIdx.z * kChunk;
    C += (size_t)blockIdx.z * cPartStride;

    int aRow[2], aKc[2];
#pragma unroll
    for (int c = 0; c < 2; c++) {
        int lin = tid + c * 256;
        aRow[c] = lin >> 3; aKc[c] = (lin & 7) * 8;
    }

    short8 rAh[2], rAl[2], rBh[2], rBl[2];
    auto LOAD = [&](int k0) {
#pragma unroll
        for (int c = 0; c < 2; c++) {
            size_t ga = (size_t)(row0 + aRow[c]) * Kp + kbase + k0 + aKc[c];
            size_t gb = (size_t)(col0 + aRow[c]) * Kp + kbase + k0 + aKc[c];
            rAh[c] = *(const short8*)(Ah + ga);
            rAl[c] = *(const short8*)(Al + ga);
            rBh[c] = *(const short8*)(Bh + gb);
            rBl[c] = *(const short8*)(Bl + gb);
        }
    };
    auto WRITE = [&](int buf) {
#pragma unroll
        for (int c = 0; c < 2; c++) {
            int o = aRow[c] * LDK + aKc[c];
            *(short8*)&Ash[buf][o] = rAh[c];
            *(short8*)&Asl[buf][o] = rAl[c];
            *(short8*)&Bsh[buf][o] = rBh[c];
            *(short8*)&Bsl[buf][o] = rBl[c];
        }
    };

    f32x4 acc[2][2];
#pragma unroll
    for (int m = 0; m < 2; m++)
#pragma unroll
        for (int n = 0; n < 2; n++) acc[m][n] = (f32x4){0.f, 0.f, 0.f, 0.f};

    LOAD(0);
    WRITE(0);
    __syncthreads();

    int nt = kChunk / GBK;
    for (int t = 0; t < nt; ++t) {
        int cur = t & 1;
        if (t + 1 < nt) LOAD((t + 1) * GBK);
#pragma unroll
        for (int ks = 0; ks < 2; ++ks) {
            short8 ah[2], al[2], bh[2], bl[2];
            int ko = ks * 32 + (lane >> 4) * 8;
#pragma unroll
            for (int m = 0; m < 2; m++) {
                int r = (wr * 32 + m * 16 + (lane & 15)) * LDK + ko;
                ah[m] = *(const short8*)&Ash[cur][r];
                al[m] = *(const short8*)&Asl[cur][r];
            }
#pragma unroll
            for (int n = 0; n < 2; n++) {
                int r = (wc * 32 + n * 16 + (lane & 15)) * LDK + ko;
                bh[n] = *(const short8*)&Bsh[cur][r];
                bl[n] = *(const short8*)&Bsl[cur][r];
            }
#pragma unroll
            for (int m = 0; m < 2; m++)
#pragma unroll
                for (int n = 0; n < 2; n++) {
                    acc[m][n] = __builtin_amdgcn_mfma_f32_16x16x32_bf16(ah[m], bh[n], acc[m][n], 0, 0, 0);
                    acc[m][n] = __builtin_amdgcn_mfma_f32_16x16x32_bf16(ah[m], bl[n], acc[m][n], 0, 0, 0);
                    acc[m][n] = __builtin_amdgcn_mfma_f32_16x16x32_bf16(al[m], bh[n], acc[m][n], 0, 0, 0);
                }
        }
        if (t + 1 < nt) WRITE(cur ^ 1);
        __syncthreads();
    }

#pragma unroll
    for (int m = 0; m < 2; m++)
#pragma unroll
        for (int n = 0; n < 2; n++)
#pragma unroll
            for (int r = 0; r < 4; r++) {
                int rr = row0 + wr * 32 + m * 16 + (lane >> 4) * 4 + r;
                int cc = col0 + wc * 32 + n * 16 + (lane & 15);
                if (headmajor)
                    C[(size_t)(cc >> 6) * (N_NODES * 64) + (size_t)rr * 64 + (cc & 63)] = acc[m][n][r];
                else
                    C[(size_t)rr * 64 + cc] = acc[m][n][r];
            }

    if (aH) {   // fused f1/f2: head == by (GBN==64)
        __shared__ float f1p[2][64], f2p[2][64];
        const float* ahp = aH + by * 128;
        int cl = lane & 15;
        float a1x = ahp[wc * 32 + cl],      a1y = ahp[wc * 32 + 16 + cl];
        float a2x = ahp[64 + wc * 32 + cl], a2y = ahp[64 + wc * 32 + 16 + cl];
#pragma unroll
        for (int m = 0; m < 2; m++)
#pragma unroll
            for (int r = 0; r < 4; r++) {
                float s1 = acc[m][0][r] * a1x + acc[m][1][r] * a1y;
                float s2 = acc[m][0][r] * a2x + acc[m][1][r] * a2y;
#pragma unroll
                for (int off = 1; off < 16; off <<= 1) {
                    s1 += __shfl_xor(s1, off);
                    s2 += __shfl_xor(s2, off);
                }
                if ((lane & 15) == 0) {
                    int rl = wr * 32 + m * 16 + (lane >> 4) * 4 + r;
                    f1p[wc][rl] = s1;
                    f2p[wc][rl] = s2;
                }
            }
        __syncthreads();
        if (tid < 64) {
            f1h[(size_t)by * N_NODES + row0 + tid] = f1p[0][tid] + f1p[1][tid];
            f2h[(size_t)by * N_NODES + row0 + tid] = f2p[0][tid] + f2p[1][tid];
        }
    }
}

// ---------------------------------------------------------------------------
// K3: attn layer 1. 512 threads = 8 waves; each wave owns TWO rows of ONE
// head. head = blockIdx&7 (XCD pinning); f2 staged to LDS. Outputs hp hi/lo.
// ---------------------------------------------------------------------------
__global__ __launch_bounds__(512, 4) void attn1(const float* __restrict__ Whh,
                                                const float* __restrict__ f1h,
                                                const float* __restrict__ f2h,
                                                const ushort* __restrict__ csr,
                                                const int* __restrict__ rowlen,
                                                short* __restrict__ hp_h,
                                                short* __restrict__ hp_l) {
    __shared__ float  f2s[N_NODES];        // 16 KB
    __shared__ float  w[16][MAXDEG];       // 16 KB
    __shared__ ushort cols[16][MAXDEG];    // 8 KB
    int lin = blockIdx.x;
    int h = lin & 7;
    int wid = threadIdx.x >> 6, lane = threadIdx.x & 63;
    int i0 = (lin >> 3) * 16 + wid * 2;
    int sA = wid * 2, sB = sA + 1;

    {   // stage f2 for this head
        const float4* f2g = (const float4*)(f2h + (size_t)h * N_NODES);
        float4 v0 = f2g[threadIdx.x];
        float4 v1 = f2g[threadIdx.x + 512];
        *(float4*)&f2s[threadIdx.x * 4] = v0;
        *(float4*)&f2s[(threadIdx.x + 512) * 4] = v1;
    }
    __syncthreads();

    float sinvR[2];
    int lenR[2];
#pragma unroll
    for (int r = 0; r < 2; r++) {
        int i = i0 + r, slot = sA + r;
        int len = rowlen[i];
        lenR[r] = len;
        const ushort* crow = csr + (size_t)i * MAXDEG;
        float f1v = f1h[(size_t)h * N_NODES + i];
        float ev[4]; int cv[4];
        float m = -1e30f;
#pragma unroll
        for (int c = 0; c < 4; c++) {
            int k = lane + c * 64;
            if (k < len) {
                int j = crow[k];
                float e = f1v + f2s[j];
                e = e > 0.f ? e : ALPHA * e;
                ev[c] = e; cv[c] = j;
                m = fmaxf(m, e);
            }
        }
#pragma unroll
        for (int off = 32; off; off >>= 1) m = fmaxf(m, __shfl_xor(m, off));
        float s = 0.f;
#pragma unroll
        for (int c = 0; c < 4; c++) {
            int k = lane + c * 64;
            if (k < len) {
                float ex = __expf(ev[c] - m);
                s += ex;
                w[slot][k] = ex;
                cols[slot][k] = (ushort)cv[c];
            }
        }
#pragma unroll
        for (int off = 32; off; off >>= 1) s += __shfl_xor(s, off);
        sinvR[r] = 1.0f / s;
    }

    int lc = lenR[0] > lenR[1] ? lenR[0] : lenR[1];
    int len8 = (lc + 7) & ~7;
    for (int k = lenR[0] + lane; k < len8; k += 64) { w[sA][k] = 0.f; cols[sA][k] = 0; }
    for (int k = lenR[1] + lane; k < len8; k += 64) { w[sB][k] = 0.f; cols[sB][k] = 0; }

    int q = lane >> 4, d = lane & 15;
    const float4* base = (const float4*)(Whh + (size_t)h * (N_NODES * 64)) + d;
    f32x4 A0 = {0.f,0.f,0.f,0.f}, A1 = A0, B0 = A0, B1 = A0;
    for (int k = 0; k < len8; k += 8) {
        int   ja0 = cols[sA][k + q];      float wa0 = w[sA][k + q];
        int   ja1 = cols[sA][k + 4 + q];  float wa1 = w[sA][k + 4 + q];
        int   jb0 = cols[sB][k + q];      float wb0 = w[sB][k + q];
        int   jb1 = cols[sB][k + 4 + q];  float wb1 = w[sB][k + 4 + q];
        float4 va0 = base[(size_t)ja0 * 16];
        float4 va1 = base[(size_t)ja1 * 16];
        float4 vb0 = base[(size_t)jb0 * 16];
        float4 vb1 = base[(size_t)jb1 * 16];
        A0[0] += wa0 * va0.x; A0[1] += wa0 * va0.y; A0[2] += wa0 * va0.z; A0[3] += wa0 * va0.w;
        A1[0] += wa1 * va1.x; A1[1] += wa1 * va1.y; A1[2] += wa1 * va1.z; A1[3] += wa1 * va1.w;
        B0[0] += wb0 * vb0.x; B0[1] += wb0 * vb0.y; B0[2] += wb0 * vb0.z; B0[3] += wb0 * vb0.w;
        B1[0] += wb1 * vb1.x; B1[1] += wb1 * vb1.y; B1[2] += wb1 * vb1.z; B1[3] += wb1 * vb1.w;
    }

#pragma unroll
    for (int r = 0; r < 2; r++) {
        float rx, ry, rz, rw;
        if (r == 0) { rx=A0[0]+A1[0]; ry=A0[1]+A1[1]; rz=A0[2]+A1[2]; rw=A0[3]+A1[3]; }
        else        { rx=B0[0]+B1[0]; ry=B0[1]+B1[1]; rz=B0[2]+B1[2]; rw=B0[3]+B1[3]; }
#pragma unroll
        for (int off = 16; off <= 32; off <<= 1) {
            rx += __shfl_xor(rx, off);
            ry += __shfl_xor(ry, off);
            rz += __shfl_xor(rz, off);
            rw += __shfl_xor(rw, off);
        }
        if (lane < 16) {
            float sinv = sinvR[r];
            float v[4] = {rx * sinv, ry * sinv, rz * sinv, rw * sinv};
            short hi[4], lo[4];
#pragma unroll
            for (int c = 0; c < 4; c++) {
                float e = v[c] > 0.f ? v[c] : __expf(v[c]) - 1.f;   // ELU
                ushort hh = f2bf(e);
                hi[c] = (short)hh;
                lo[c] = (short)f2bf(e - bf2f(hh));
            }
            size_t o = (size_t)(i0 + r) * 512 + h * 64 + d * 4;
            *(short4*)(hp_h + o) = make_short4(hi[0], hi[1], hi[2], hi[3]);
            *(short4*)(hp_l + o) = make_short4(lo[0], lo[1], lo[2], lo[3]);
        }
    }
}

// ---------------------------------------------------------------------------
// K4: sum gemm2 split-K partials -> Wh2, compute f1o/f2o. 4 rows/block.
// ---------------------------------------------------------------------------
__global__ __launch_bounds__(256) void f2sum(const float* __restrict__ part,
                                             const float* __restrict__ a,
                                             float* __restrict__ Wh2,
                                             float* __restrict__ f1o,
                                             float* __restrict__ f2o) {
    int wid = threadIdx.x >> 6, l = threadIdx.x & 63;
    int i = blockIdx.x * 4 + wid;
    size_t o = (size_t)i * 64 + l;
    const size_t S = (size_t)N_NODES * 64;
    float v = part[o] + part[o + S] + part[o + 2 * S] + part[o + 3 * S];
    Wh2[o] = v;
    float p1 = v * a[l], p2 = v * a[64 + l];
#pragma unroll
    for (int off = 32; off; off >>= 1) {
        p1 += __shfl_xor(p1, off);
        p2 += __shfl_xor(p2, off);
    }
    if (l == 0) { f1o[i] = p1; f2o[i] = p2; }
}

// ---------------------------------------------------------------------------
// K5: attn layer 2 + first GCN matmul; f2o staged to LDS; out pre-scaled.
// ---------------------------------------------------------------------------
__global__ __launch_bounds__(256, 6) void attn2_g0(const float* __restrict__ Wh2,
                                                   const float* __restrict__ f1o,
                                                   const float* __restrict__ f2o,
                                                   const ushort* __restrict__ csr,
                                                   const int* __restrict__ rowlen,
                                                   const float* __restrict__ W0,
                                                   const float* __restrict__ dinv,
                                                   float* __restrict__ t0) {
    __shared__ float  f2s[N_NODES];      // 16 KB
    __shared__ float  w[4][MAXDEG];
    __shared__ ushort cl[4][MAXDEG];
    __shared__ float  hrow[4][64];
    int wid = threadIdx.x >> 6, lane = threadIdx.x & 63;
    int i = blockIdx.x * 4 + wid;

    {
        const float4* f2g = (const float4*)f2o;
#pragma unroll
        for (int c = 0; c < 4; c++) {
            int idx = threadIdx.x + c * 256;
            *(float4*)&f2s[idx * 4] = f2g[idx];
        }
    }
    __syncthreads();

    int len = rowlen[i];
    const ushort* crow = csr + (size_t)i * MAXDEG;
    float myf1 = f1o[i];

    float ev[4]; int cv[4];
    float m = -1e30f;
#pragma unroll
    for (int c = 0; c < 4; c++) {
        int k = lane + c * 64;
        if (k < len) {
            int j = crow[k];
            float e = myf1 + f2s[j];
            e = e > 0.f ? e : ALPHA * e;
            ev[c] = e; cv[c] = j;
            m = fmaxf(m, e);
        }
    }
#pragma unroll
    for (int off = 32; off; off >>= 1) m = fmaxf(m, __shfl_xor(m, off));
    float s = 0.f;
#pragma unroll
    for (int c = 0; c < 4; c++) {
        int k = lane + c * 64;
        if (k < len) {
            float ex = __expf(ev[c] - m);
            s += ex;
            w[wid][k] = ex;
            cl[wid][k] = (ushort)cv[c];
        }
    }
#pragma unroll
    for (int off = 32; off; off >>= 1) s += __shfl_xor(s, off);
    float sinv = 1.0f / s;

    int len16 = (len + 15) & ~15;
    if (lane < len16 - len) {
        w[wid][len + lane] = 0.f;
        cl[wid][len + lane] = 0;
    }

    int q = lane >> 4, d = lane & 15;
    const float4* base = (const float4*)Wh2 + d;
    f32x4 A0 = {0.f,0.f,0.f,0.f}, A1 = A0, A2 = A0, A3 = A0;
    for (int k = 0; k < len16; k += 16) {
        int   j0 = cl[wid][k + q];       float w0 = w[wid][k + q];
        int   j1 = cl[wid][k + 4 + q];   float w1 = w[wid][k + 4 + q];
        int   j2 = cl[wid][k + 8 + q];   float w2 = w[wid][k + 8 + q];
        int   j3 = cl[wid][k + 12 + q];  float w3 = w[wid][k + 12 + q];
        float4 v0 = base[(size_t)j0 * 16];
        float4 v1 = base[(size_t)j1 * 16];
        float4 v2 = base[(size_t)j2 * 16];
        float4 v3 = base[(size_t)j3 * 16];
        A0[0] += w0 * v0.x; A0[1] += w0 * v0.y; A0[2] += w0 * v0.z; A0[3] += w0 * v0.w;
        A1[0] += w1 * v1.x; A1[1] += w1 * v1.y; A1[2] += w1 * v1.z; A1[3] += w1 * v1.w;
        A2[0] += w2 * v2.x; A2[1] += w2 * v2.y; A2[2] += w2 * v2.z; A2[3] += w2 * v2.w;
        A3[0] += w3 * v3.x; A3[1] += w3 * v3.y; A3[2] += w3 * v3.z; A3[3] += w3 * v3.w;
    }
    float rx = (A0[0] + A1[0]) + (A2[0] + A3[0]);
    float ry = (A0[1] + A1[1]) + (A2[1] + A3[1]);
    float rz = (A0[2] + A1[2]) + (A2[2] + A3[2]);
    float rw = (A0[3] + A1[3]) + (A2[3] + A3[3]);
#pragma unroll
    for (int off = 16; off <= 32; off <<= 1) {
        rx += __shfl_xor(rx, off);
        ry += __shfl_xor(ry, off);
        rz += __shfl_xor(rz, off);
        rw += __shfl_xor(rw, off);
    }
    if (lane < 16) {
        float4 r = make_float4(rx * sinv, ry * sinv, rz * sinv, rw * sinv);
        *(float4*)&hrow[wid][d * 4] = r;
    }

    float ox = 0.f, oy = 0.f, oz = 0.f, ow = 0.f;
#pragma unroll
    for (int it = 0; it < 16; it++) {
        int kk = q * 16 + it;
        float hv = hrow[wid][kk];
        float4 wv = *(const float4*)(W0 + kk * 64 + d * 4);
        ox += hv * wv.x; oy += hv * wv.y; oz += hv * wv.z; ow += hv * wv.w;
    }
#pragma unroll
    for (int off = 16; off <= 32; off <<= 1) {
        ox += __shfl_xor(ox, off);
        oy += __shfl_xor(oy, off);
        oz += __shfl_xor(oz, off);
        ow += __shfl_xor(ow, off);
    }
    if (lane < 16) {
        float di = dinv[i];
        *(float4*)(t0 + (size_t)i * 64 + d * 4) =
            make_float4(ox * di, oy * di, oz * di, ow * di);
    }
}

// ---------------------------------------------------------------------------
// K6: GCN step: h = relu(dinv_i * sum t'_j); out = dinv_i * (h @ W).
// ---------------------------------------------------------------------------
__global__ __launch_bounds__(256, 6) void spmv_gemm(const float* __restrict__ t,
                                                    const ushort* __restrict__ csr,
                                                    const int* __restrict__ rowlen,
                                                    const float* __restrict__ W,
                                                    const float* __restrict__ dinv,
                                                    float* __restrict__ out) {
    __shared__ float hrow[4][64];
    int wid = threadIdx.x >> 6, lane = threadIdx.x & 63;
    int i = blockIdx.x * 4 + wid;
    int len = rowlen[i];
    const ushort* ci = csr + (size_t)i * MAXDEG;
    int q = lane >> 4, d = lane & 15;
    const float4* base = (const float4*)t + d;
    int len16 = (len + 15) & ~15;
    f32x4 A0 = {0.f,0.f,0.f,0.f}, A1 = A0, A2 = A0, A3 = A0;
    for (int k = 0; k < len16; k += 16) {
        int k0 = k + q, k1 = k + 4 + q, k2 = k + 8 + q, k3 = k + 12 + q;
        float m0 = k0 < len ? 1.f : 0.f;
        float m1 = k1 < len ? 1.f : 0.f;
        float m2 = k2 < len ? 1.f : 0.f;
        float m3 = k3 < len ? 1.f : 0.f;
        int j0 = ci[k0 < len ? k0 : 0];
        int j1 = ci[k1 < len ? k1 : 0];
        int j2 = ci[k2 < len ? k2 : 0];
        int j3 = ci[k3 < len ? k3 : 0];
        float4 v0 = base[(size_t)j0 * 16];
        float4 v1 = base[(size_t)j1 * 16];
        float4 v2 = base[(size_t)j2 * 16];
        float4 v3 = base[(size_t)j3 * 16];
        A0[0] += m0 * v0.x; A0[1] += m0 * v0.y; A0[2] += m0 * v0.z; A0[3] += m0 * v0.w;
        A1[0] += m1 * v1.x; A1[1] += m1 * v1.y; A1[2] += m1 * v1.z; A1[3] += m1 * v1.w;
        A2[0] += m2 * v2.x; A2[1] += m2 * v2.y; A2[2] += m2 * v2.z; A2[3] += m2 * v2.w;
        A3[0] += m3 * v3.x; A3[1] += m3 * v3.y; A3[2] += m3 * v3.z; A3[3] += m3 * v3.w;
    }
    float rx = (A0[0] + A1[0]) + (A2[0] + A3[0]);
    float ry = (A0[1] + A1[1]) + (A2[1] + A3[1]);
    float rz = (A0[2] + A1[2]) + (A2[2] + A3[2]);
    float rw = (A0[3] + A1[3]) + (A2[3] + A3[3]);
#pragma unroll
    for (int off = 16; off <= 32; off <<= 1) {
        rx += __shfl_xor(rx, off);
        ry += __shfl_xor(ry, off);
        rz += __shfl_xor(rz, off);
        rw += __shfl_xor(rw, off);
    }
    float di = dinv[i];
    if (lane < 16) {
        float4 r = make_float4(fmaxf(rx * di, 0.f), fmaxf(ry * di, 0.f),
                               fmaxf(rz * di, 0.f), fmaxf(rw * di, 0.f));
        *(float4*)&hrow[wid][d * 4] = r;
    }

    float ox = 0.f, oy = 0.f, oz = 0.f, ow = 0.f;
#pragma unroll
    for (int it = 0; it < 16; it++) {
        int kk = q * 16 + it;
        float hv = hrow[wid][kk];
        float4 wv = *(const float4*)(W + kk * 64 + d * 4);
        ox += hv * wv.x; oy += hv * wv.y; oz += hv * wv.z; ow += hv * wv.w;
    }
#pragma unroll
    for (int off = 16; off <= 32; off <<= 1) {
        ox += __shfl_xor(ox, off);
        oy += __shfl_xor(oy, off);
        oz += __shfl_xor(oz, off);
        ow += __shfl_xor(ow, off);
    }
    if (lane < 16)
        *(float4*)(out + (size_t)i * 64 + d * 4) =
            make_float4(ox * di, oy * di, oz * di, ow * di);
}

// ---------------------------------------------------------------------------
// K7: final GCN step into classifier. Gather; 64x8 matmul.
// ---------------------------------------------------------------------------
__global__ __launch_bounds__(256, 4) void spmv_cls(const float* __restrict__ t,
                                                   const ushort* __restrict__ csr,
                                                   const int* __restrict__ rowlen,
                                                   const float* __restrict__ Wc,
                                                   const float* __restrict__ dinv,
                                                   float* __restrict__ t8) {
    __shared__ float hrow[4][64];
    int wid = threadIdx.x >> 6, lane = threadIdx.x & 63;
    int i = blockIdx.x * 4 + wid;
    int len = rowlen[i];
    const ushort* ci = csr + (size_t)i * MAXDEG;
    int q = lane >> 4, d = lane & 15;
    const float4* base = (const float4*)t + d;
    int len16 = (len + 15) & ~15;
    f32x4 A0 = {0.f,0.f,0.f,0.f}, A1 = A0, A2 = A0, A3 = A0;
    for (int k = 0; k < len16; k += 16) {
        int k0 = k + q, k1 = k + 4 + q, k2 = k + 8 + q, k3 = k + 12 + q;
        float m0 = k0 < len ? 1.f : 0.f;
        float m1 = k1 < len ? 1.f : 0.f;
        float m2 = k2 < len ? 1.f : 0.f;
        float m3 = k3 < len ? 1.f : 0.f;
        int j0 = ci[k0 < len ? k0 : 0];
        int j1 = ci[k1 < len ? k1 : 0];
        int j2 = ci[k2 < len ? k2 : 0];
        int j3 = ci[k3 < len ? k3 : 0];
        float4 v0 = base[(size_t)j0 * 16];
        float4 v1 = base[(size_t)j1 * 16];
        float4 v2 = base[(size_t)j2 * 16];
        float4 v3 = base[(size_t)j3 * 16];
        A0[0] += m0 * v0.x; A0[1] += m0 * v0.y; A0[2] += m0 * v0.z; A0[3] += m0 * v0.w;
        A1[0] += m1 * v1.x; A1[1] += m1 * v1.y; A1[2] += m1 * v1.z; A1[3] += m1 * v1.w;
        A2[0] += m2 * v2.x; A2[1] += m2 * v2.y; A2[2] += m2 * v2.z; A2[3] += m2 * v2.w;
        A3[0] += m3 * v3.x; A3[1] += m3 * v3.y; A3[2] += m3 * v3.z; A3[3] += m3 * v3.w;
    }
    float rx = (A0[0] + A1[0]) + (A2[0] + A3[0]);
    float ry = (A0[1] + A1[1]) + (A2[1] + A3[1]);
    float rz = (A0[2] + A1[2]) + (A2[2] + A3[2]);
    float rw = (A0[3] + A1[3]) + (A2[3] + A3[3]);
#pragma unroll
    for (int off = 16; off <= 32; off <<= 1) {
        rx += __shfl_xor(rx, off);
        ry += __shfl_xor(ry, off);
        rz += __shfl_xor(rz, off);
        rw += __shfl_xor(rw, off);
    }
    float di = dinv[i];
    if (lane < 16) {
        float4 r = make_float4(fmaxf(rx * di, 0.f), fmaxf(ry * di, 0.f),
                               fmaxf(rz * di, 0.f), fmaxf(rw * di, 0.f));
        *(float4*)&hrow[wid][d * 4] = r;
    }
    int col = lane & 7, k0s = (lane >> 3) * 8;
    float o = 0.f;
#pragma unroll
    for (int kk = 0; kk < 8; kk++) o += hrow[wid][k0s + kk] * Wc[(k0s + kk) * 8 + col];
    o += __shfl_down(o, 32);
    o += __shfl_down(o, 16);
    o += __shfl_down(o, 8);
    if (lane < 8) t8[(size_t)i * 8 + lane] = o * di;
}

// ---------------------------------------------------------------------------
// K8: final propagation on pre-scaled t8': out_i = dinv_i * sum t8'_j.
// ---------------------------------------------------------------------------
__global__ __launch_bounds__(256) void spmv8(const float* __restrict__ t8,
                                             const ushort* __restrict__ csr,
                                             const int* __restrict__ rowlen,
                                             const float* __restrict__ dinv,
                                             float* __restrict__ out) {
    int wid = threadIdx.x >> 6, lane = threadIdx.x & 63;
    int i = blockIdx.x * 4 + wid;
    int len = rowlen[i];
    const ushort* ci = csr + (size_t)i * MAXDEG;
    int col = lane & 7, chunk = lane >> 3;
    float acc = 0.f;
    for (int k = chunk; k < len; k += 8)
        acc += t8[(size_t)ci[k] * 8 + col];
    acc += __shfl_down(acc, 32);
    acc += __shfl_down(acc, 16);
    acc += __shfl_down(acc, 8);
    if (lane < 8) out[(size_t)i * 8 + lane] = acc * dinv[i];
}

// ---------------------------------------------------------------------------
extern "C" void kernel_launch(void* const* d_in, const int* in_sizes, int n_in,
                              void* d_out, int out_size, void* d_ws, size_t ws_size,
                              hipStream_t stream) {
    const float* x       = (const float*)d_in[0];
    const int*   adj     = (const int*)d_in[1];
    const float* W_heads = (const float*)d_in[2];
    const float* a_heads = (const float*)d_in[3];
    const float* W_out   = (const float*)d_in[4];
    const float* a_out   = (const float*)d_in[5];
    const float* W_gcn   = (const float*)d_in[6];
    const float* W_cls   = (const float*)d_in[7];
    float* outp = (float*)d_out;

    char* p = (char*)d_ws;
    short*  x_h    = (short*)p;  p += (size_t)N_NODES * NFEAT * 2;    // 8 MB
    short*  x_l    = (short*)p;  p += (size_t)N_NODES * NFEAT * 2;    // 8 MB
    short*  W3h    = (short*)p;  p += (size_t)512 * NFEAT * 2;        // 1 MB
    short*  W3l    = (short*)p;  p += (size_t)512 * NFEAT * 2;        // 1 MB
    short*  W2h    = (short*)p;  p += (size_t)64 * 512 * 2;
    short*  W2l    = (short*)p;  p += (size_t)64 * 512 * 2;
    float*  Whh    = (float*)p;  p += (size_t)NHEADS * N_NODES * 64 * 4;  // 8 MB
    float*  f1h    = (float*)p;  p += (size_t)NHEADS * N_NODES * 4;
    float*  f2h    = (float*)p;  p += (size_t)NHEADS * N_NODES * 4;
    float*  Wh2    = (float*)p;  p += (size_t)N_NODES * 64 * 4;
    float*  f1o    = (float*)p;  p += (size_t)N_NODES * 4;
    float*  f2o    = (float*)p;  p += (size_t)N_NODES * 4;
    float*  tA     = (float*)p;  p += (size_t)N_NODES * 64 * 4;
    float*  tB     = (float*)p;  p += (size_t)N_NODES * 64 * 4;
    float*  t8     = (float*)p;  p += (size_t)N_NODES * 8 * 4;
    float*  dinv   = (float*)p;  p += (size_t)N_NODES * 4;
    int*    rowlen = (int*)p;    p += (size_t)N_NODES * 4;
    ushort* csr    = (ushort*)p; p += (size_t)N_NODES * MAXDEG * 2;   // 2 MB

    // aliases: x_h/x_l dead after gemm1. hp hi/lo each 4 MB; part 4 MB.
    short* hp_h = x_h;                                   // [0, 4 MB) of x_h
    short* hp_l = x_l;                                   // [0, 4 MB) of x_l
    float* part = (float*)((char*)x_h + (4u << 20));     // [4, 8 MB) of x_h

    // K1: prep (splits) + CSR build in one launch
    prep_all<<<4096 + 128 + 8 + 1024, 256, 0, stream>>>(
        x, adj, W_heads, W_out, x_h, x_l, W3h, W3l, W2h, W2l, csr, rowlen, dinv);

    // K2: gemm1 (bf16x3, 3 MFMA/frag) -> Whh head-major + fused f1/f2
    gemm3<<<512, 256, 0, stream>>>(x_h, x_l, W3h, W3l, Whh, NFEAT, NFEAT, 0,
                                   1, 1, a_heads, f1h, f2h);

    // K3: attn layer 1 (+ELU), 2 rows/wave -> hp hi/lo [4096][512]
    attn1<<<N_NODES * NHEADS / 16, 512, 0, stream>>>(Whh, f1h, f2h, csr, rowlen,
                                                     hp_h, hp_l);

    // K4: gemm2 partials = hp @ W2 (K=512, split-K=4 -> 256 blocks)
    gemm3<<<dim3(N_NODES / GBM, 1, 4), 256, 0, stream>>>(
        hp_h, hp_l, W2h, W2l, part, 512, 128, N_NODES * 64,
        0, 0, nullptr, nullptr, nullptr);

    // K5: partial sum + f1o/f2o
    f2sum<<<N_NODES / 4, 256, 0, stream>>>(part, a_out, Wh2, f1o, f2o);

    // K6: attn layer 2 + W_gcn[0]
    attn2_g0<<<N_NODES / 4, 256, 0, stream>>>(Wh2, f1o, f2o, csr, rowlen, W_gcn, dinv, tA);

    // K7-8: GCN blocks 1,2
    spmv_gemm<<<N_NODES / 4, 256, 0, stream>>>(tA, csr, rowlen, W_gcn + 4096, dinv, tB);
    spmv_gemm<<<N_NODES / 4, 256, 0, stream>>>(tB, csr, rowlen, W_gcn + 8192, dinv, tA);

    // K9-10: final block + classifier, last propagation
    spmv_cls<<<N_NODES / 4, 256, 0, stream>>>(tA, csr, rowlen, W_cls, dinv, t8);
    spmv8<<<N_NODES / 4, 256, 0, stream>>>(t8, csr, rowlen, dinv, outp);
}